// Round 6
// baseline (339.492 us; speedup 1.0000x reference)
//
#include <hip/hip_runtime.h>
#include <cstdint>
#include <math.h>

// ---------------------------------------------------------------------------
// AttentionBlock: GroupNorm(32) -> 1x1 conv QKV -> MHA(8 heads, hd=64)
//                 -> 1x1 conv proj -> +residual.   B=16, C=512, N=H*W=1024.
// I/O tensors are FP32. Internal math: bf16 MFMA.
//
// ws layout (byte offsets):
//   0        float2 stats[512]          (mean, rstd) per (b, group)
//   64K      qwb  bf16[1536*512]        qkv_w converted to bf16
//   2M       pwb  bf16[512*512]         proj_w converted to bf16
//   4M       hnt  (B, N, C)   bf16      groupnormed x, (n, c); REUSED as ont
//   20M      qkt  (B, N, 1024) bf16     cols [0,512)=q, [512,1024)=k
//   52M      vt   (B, 512, N) bf16      v channel-major (d, n)
// ---------------------------------------------------------------------------

typedef __bf16 bf16;
typedef __attribute__((ext_vector_type(8))) __bf16 bf16x8;
typedef __attribute__((ext_vector_type(4))) float f32x4;
typedef __attribute__((ext_vector_type(4))) short s16x4;

union U8 { uint4 u4; bf16x8 v; bf16 h[8]; };
union U4 { ushort4 u; bf16 h[4]; };
union UB4 { ushort4 u; s16x4 s; bf16 h[4]; };
union F4 { float4 v; float f[4]; };

typedef __attribute__((address_space(1))) void* gp1;
typedef __attribute__((address_space(3))) void* lp3;

__device__ __forceinline__ void async16(const void* g, void* l) {
  __builtin_amdgcn_global_load_lds((gp1)g, (lp3)l, 16, 0, 0);
}

#define LOG2E 1.44269504f

// ---------------------------------------------------------------------------
// Kernel 0: convert fp32 weights to bf16. qw: 1536x512, pw: 512x512.
// ---------------------------------------------------------------------------
__global__ __launch_bounds__(256) void cvt_w(const float* __restrict__ qw,
                                             const float* __restrict__ pw,
                                             bf16* __restrict__ qwb,
                                             bf16* __restrict__ pwb) {
  int i = blockIdx.x * 256 + threadIdx.x;     // float4 index; 262144 total
  F4 v; bf16* dst;
  if (i < 196608) { v.v = ((const float4*)qw)[i]; dst = qwb + (size_t)i * 4; }
  else { v.v = ((const float4*)pw)[i - 196608]; dst = pwb + (size_t)(i - 196608) * 4; }
  U4 o;
#pragma unroll
  for (int j = 0; j < 4; j++) o.h[j] = (bf16)v.f[j];
  *(ushort4*)dst = o.u;
}

// ---------------------------------------------------------------------------
// Kernel 1: per-(b,group) mean/rstd. One block per (b,g): 16ch x 1024 fp32.
// ---------------------------------------------------------------------------
__global__ __launch_bounds__(256) void gn_stats(const float* __restrict__ x,
                                                float2* __restrict__ stats) {
  int bg = blockIdx.x;                         // b*32 + g
  const float* base = x + (size_t)bg * 16384;
  int t = threadIdx.x;
  float s = 0.f, ss = 0.f;
#pragma unroll
  for (int p = 0; p < 16; p++) {
    F4 u; u.v = *(const float4*)(base + (size_t)(p * 256 + t) * 4);
#pragma unroll
    for (int i = 0; i < 4; i++) { float v = u.f[i]; s += v; ss += v * v; }
  }
  for (int off = 1; off < 64; off <<= 1) { s += __shfl_xor(s, off); ss += __shfl_xor(ss, off); }
  __shared__ float red[8];
  int w = t >> 6;
  if ((t & 63) == 0) { red[w] = s; red[4 + w] = ss; }
  __syncthreads();
  if (t == 0) {
    float S = red[0] + red[1] + red[2] + red[3];
    float SS = red[4] + red[5] + red[6] + red[7];
    float mean = S * (1.f / 16384.f);
    float var = SS * (1.f / 16384.f) - mean * mean;
    stats[bg] = make_float2(mean, rsqrtf(var + 1e-5f));
  }
}

// ---------------------------------------------------------------------------
// Kernel 2: hn_t[b][n][c] = bf16((x[b][c][n]-mean)*rstd*w + bias), transposed.
// ---------------------------------------------------------------------------
__global__ __launch_bounds__(256) void gn_apply(const float* __restrict__ x,
                                                const float* __restrict__ nwp,
                                                const float* __restrict__ nbp,
                                                const float2* __restrict__ stats,
                                                bf16* __restrict__ hnt) {
  int b = blockIdx.z, nt = blockIdx.y, ct = blockIdx.x;
  int t = threadIdx.x, w = t >> 6, l = t & 63;
  int wc = w & 1, wn = w >> 1;
  int cb = ct * 128 + wc * 64 + (l & 7) * 8;   // 8 channels per lane
  int n0 = nt * 64 + wn * 32 + (l >> 3) * 4;   // 4 n per lane
  float2 ms = stats[b * 32 + (cb >> 4)];
  float wgt[8], bia[8];
#pragma unroll
  for (int i = 0; i < 8; i++) {
    float wi = nwp[cb + i] * ms.y;
    wgt[i] = wi;
    bia[i] = nbp[cb + i] - ms.x * wi;
  }
  F4 in[8];
  const float* xb = x + ((size_t)b * 512 + cb) * 1024 + n0;
#pragma unroll
  for (int i = 0; i < 8; i++) in[i].v = *(const float4*)(xb + (size_t)i * 1024);
  bf16* ob = hnt + ((size_t)b * 1024 + n0) * 512 + cb;
#pragma unroll
  for (int j = 0; j < 4; j++) {
    U8 o;
#pragma unroll
    for (int i = 0; i < 8; i++) o.h[i] = (bf16)(in[i].f[j] * wgt[i] + bia[i]);
    *(uint4*)(ob + (size_t)j * 512) = o.u4;
  }
}

// ---------------------------------------------------------------------------
// Shared gemm-BT core (m97 recipe).
// ---------------------------------------------------------------------------
__device__ __forceinline__ void gemm_bt_core(const bf16* ga0, const bf16* gb0,
                                             bf16* At, bf16* Bt,
                                             f32x4 (&acc)[4][4], int w, int l) {
  const bf16* ga = ga0 + (size_t)(w * 16 + (l >> 2)) * 512 + (l & 3) * 8;
  const bf16* gb = gb0 + (size_t)(w * 16 + (l >> 2)) * 512 + (l & 3) * 8;
  int wr = w >> 1, wc = w & 1;
  const bf16* Ab = At + (wr * 64 + (l & 15)) * 32 + (l >> 4) * 8;
  const bf16* Bb = Bt + (wc * 64 + (l & 15)) * 32 + (l >> 4) * 8;
  bf16* lA = At + w * 16 * 32;
  bf16* lB = Bt + w * 16 * 32;
  for (int k0 = 0; k0 < 512; k0 += 32) {
    async16(ga + k0, lA);
    async16(ga + 64 * 512 + k0, lA + 64 * 32);
    async16(gb + k0, lB);
    async16(gb + 64 * 512 + k0, lB + 64 * 32);
    __syncthreads();
    bf16x8 af[4], bfr[4];
#pragma unroll
    for (int i = 0; i < 4; i++) {
      af[i] = *(const bf16x8*)(Ab + i * 512);
      bfr[i] = *(const bf16x8*)(Bb + i * 512);
    }
#pragma unroll
    for (int i = 0; i < 4; i++)
#pragma unroll
      for (int j = 0; j < 4; j++)
        acc[i][j] = __builtin_amdgcn_mfma_f32_16x16x32_bf16(af[i], bfr[j], acc[i][j], 0, 0, 0);
    __syncthreads();
  }
}

// ---------------------------------------------------------------------------
// Kernel 3: qkv projection GEMM.  Grid (ot=12, nt=8, b=16).
// ---------------------------------------------------------------------------
__global__ __launch_bounds__(256, 2) void qkv_gemm(const bf16* __restrict__ hnt,
                                                   const bf16* __restrict__ qwb,
                                                   const float* __restrict__ qb,
                                                   bf16* __restrict__ qkt,
                                                   bf16* __restrict__ vt) {
  __shared__ bf16 At[128 * 32];
  __shared__ bf16 Bt[128 * 32];
  int b = blockIdx.z, mt = blockIdx.y, ot = blockIdx.x;
  int m0 = mt * 128, o0 = ot * 128;
  int t = threadIdx.x, w = t >> 6, l = t & 63;
  f32x4 acc[4][4] = {};
  gemm_bt_core(hnt + ((size_t)b * 1024 + m0) * 512, qwb + (size_t)o0 * 512, At, Bt, acc, w, l);

  int wr = w >> 1, wc = w & 1, quad = l >> 4, li = l & 15;
#pragma unroll
  for (int i = 0; i < 4; i++) {
    int gn = m0 + wr * 64 + i * 16 + quad * 4;
#pragma unroll
    for (int j = 0; j < 4; j++) {
      int go = o0 + wc * 64 + j * 16 + li;
      float bias = qb[go];
      if (ot < 8) {             // q,k region: (n, o) layout
        bf16* p = qkt + ((size_t)b * 1024 + gn) * 1024 + go;
#pragma unroll
        for (int r = 0; r < 4; r++) p[(size_t)r * 1024] = (bf16)(acc[i][j][r] + bias);
      } else {                  // v region: transposed (d, n), 8B stores
        U4 pk;
#pragma unroll
        for (int r = 0; r < 4; r++) pk.h[r] = (bf16)(acc[i][j][r] + bias);
        *(ushort4*)(vt + ((size_t)b * 512 + (go - 1024)) * 1024 + gn) = pk.u;
      }
    }
  }
}

// ---------------------------------------------------------------------------
// Kernel 4: flash attention, S^T formulation, zero LDS, chunked softmax,
// SOFTWARE-PIPELINED: K for chunk i+1 prefetched during chunk i's softmax/PV;
// V for chunk i issued at loop top (hidden under S-MFMAs + softmax).
// Ballot-gated rescale: of/lrun rescale skipped when no lane saw a new max.
// Grid (bh=128, qt=8): all 8 q-tiles of one (b,h) share an XCD.
// ---------------------------------------------------------------------------
__global__ __launch_bounds__(256, 4) void attn(const bf16* __restrict__ qkt,
                                               const bf16* __restrict__ vt,
                                               bf16* __restrict__ ont) {
  int bh = blockIdx.x;                 // b*8 + h
  int b = bh >> 3, h = bh & 7;
  int qt = blockIdx.y;
  int t = threadIdx.x, w = t >> 6, l = t & 63;
  int quad = l >> 4, li = l & 15;
  int q0 = qt * 128 + w * 32;

  const bf16* qb = qkt + (size_t)b * 1048576 + h * 64;
  const bf16* kb = qb + 512;
  const bf16* vb = vt + ((size_t)b * 512 + h * 64) * 1024;

  // Q frags (B-operand of 16x16x32): scale = 0.125 * log2(e) folded in.
  const float QS = 0.125f * LOG2E;
  bf16x8 qfr[2][2];
#pragma unroll
  for (int qf = 0; qf < 2; qf++)
#pragma unroll
    for (int ks = 0; ks < 2; ks++) {
      U8 u;
      u.u4 = *(const uint4*)(qb + (size_t)(q0 + qf * 16 + li) * 1024 + ks * 32 + quad * 8);
#pragma unroll
      for (int i = 0; i < 8; i++) u.h[i] = (bf16)((float)u.h[i] * QS);
      qfr[qf][ks] = u.v;
    }

  float mrun[2] = {-INFINITY, -INFINITY}, lrun[2] = {0.f, 0.f};
  f32x4 of[4][2] = {};   // O^T accum [df][qf]: row d=df*16+quad*4+r, col q=qf*16+li

  // ---- prefetch K chunk 0 ----
  U8 ka[2], kc[2];
#pragma unroll
  for (int kf = 0; kf < 2; kf++) {
    const bf16* kr = kb + (size_t)(kf * 16 + li) * 1024 + quad * 8;
    ka[kf].u4 = *(const uint4*)kr;
    kc[kf].u4 = *(const uint4*)(kr + 32);
  }

  for (int k0 = 0; k0 < 1024; k0 += 32) {
    // ---- V frags for THIS chunk: issue first, consumed after softmax ----
    UB4 va[2][4];
#pragma unroll
    for (int kf = 0; kf < 2; kf++)
#pragma unroll
      for (int df = 0; df < 4; df++)
        va[kf][df].u = *(const ushort4*)(vb + (size_t)(df * 16 + li) * 1024 + k0 + kf * 16 + quad * 4);
    // ---- S^T chunk with resident K: st[qf][kf], k = k0+kf*16+quad*4+r ----
    f32x4 st[2][2] = {};
#pragma unroll
    for (int kf = 0; kf < 2; kf++) {
      st[0][kf] = __builtin_amdgcn_mfma_f32_16x16x32_bf16(ka[kf].v, qfr[0][0], st[0][kf], 0, 0, 0);
      st[1][kf] = __builtin_amdgcn_mfma_f32_16x16x32_bf16(ka[kf].v, qfr[1][0], st[1][kf], 0, 0, 0);
      st[0][kf] = __builtin_amdgcn_mfma_f32_16x16x32_bf16(kc[kf].v, qfr[0][1], st[0][kf], 0, 0, 0);
      st[1][kf] = __builtin_amdgcn_mfma_f32_16x16x32_bf16(kc[kf].v, qfr[1][1], st[1][kf], 0, 0, 0);
    }
    // ---- prefetch K for NEXT chunk (wrap on last iter; result unused) ----
    U8 nka[2], nkc[2];
    int kn = (k0 + 32) & 1023;
#pragma unroll
    for (int kf = 0; kf < 2; kf++) {
      const bf16* kr = kb + (size_t)(kn + kf * 16 + li) * 1024 + quad * 8;
      nka[kf].u4 = *(const uint4*)kr;
      nkc[kf].u4 = *(const uint4*)(kr + 32);
    }
    // ---- online softmax over the 32-k chunk ----
    UB4 pfr[2][2];
#pragma unroll
    for (int qf = 0; qf < 2; qf++) {
      f32x4 vm = st[qf][0];
#pragma unroll
      for (int r = 0; r < 4; r++) vm[r] = fmaxf(vm[r], st[qf][1][r]);
      float mt = fmaxf(fmaxf(vm[0], vm[1]), fmaxf(vm[2], vm[3]));
      mt = fmaxf(mt, __shfl_xor(mt, 16));
      mt = fmaxf(mt, __shfl_xor(mt, 32));
      float mold = mrun[qf];
      float mnew = fmaxf(mold, mt);
      mrun[qf] = mnew;
      f32x4 vs = {};
#pragma unroll
      for (int kf = 0; kf < 2; kf++)
#pragma unroll
        for (int r = 0; r < 4; r++) {
          float e = __builtin_amdgcn_exp2f(st[qf][kf][r] - mnew);
          vs[r] += e;
          pfr[qf][kf].h[r] = (bf16)e;
        }
      float ls = (vs[0] + vs[1]) + (vs[2] + vs[3]);
      ls += __shfl_xor(ls, 16);
      ls += __shfl_xor(ls, 32);
      if (__ballot(mnew > mold)) {       // any lane saw a new max -> rescale
        float alpha = __builtin_amdgcn_exp2f(mold - mnew);
        lrun[qf] = lrun[qf] * alpha + ls;
#pragma unroll
        for (int df = 0; df < 4; df++)
#pragma unroll
          for (int r = 0; r < 4; r++) of[df][qf][r] *= alpha;
      } else {
        lrun[qf] += ls;
      }
    }
    // ---- O^T += V^T P^T (16x16x16, P^T straight from registers) ----
#pragma unroll
    for (int kf = 0; kf < 2; kf++)
#pragma unroll
      for (int df = 0; df < 4; df++)
#pragma unroll
        for (int qf = 0; qf < 2; qf++)
          of[df][qf] = __builtin_amdgcn_mfma_f32_16x16x16bf16_1k(va[kf][df].s, pfr[qf][kf].s, of[df][qf], 0, 0, 0);
    // ---- rotate K double-buffer ----
#pragma unroll
    for (int kf = 0; kf < 2; kf++) { ka[kf] = nka[kf]; kc[kf] = nkc[kf]; }
  }
  // ---- epilogue: O[q][d] = O^T/l, packed 8B stores ----
#pragma unroll
  for (int qf = 0; qf < 2; qf++) {
    float inv = 1.f / lrun[qf];
    bf16* ob = ont + ((size_t)b * 1024 + q0 + qf * 16 + li) * 512 + h * 64 + quad * 4;
#pragma unroll
    for (int df = 0; df < 4; df++) {
      U4 pk;
#pragma unroll
      for (int r = 0; r < 4; r++) pk.h[r] = (bf16)(of[df][qf][r] * inv);
      *(ushort4*)(ob + df * 16) = pk.u;
    }
  }
}

// ---------------------------------------------------------------------------
// Kernel 5: proj GEMM + residual. Grid (4, 8, 16).
// ---------------------------------------------------------------------------
__global__ __launch_bounds__(256, 2) void proj_gemm(const bf16* __restrict__ ont,
                                                    const bf16* __restrict__ pwb,
                                                    const float* __restrict__ pb,
                                                    const float* __restrict__ x,
                                                    float* __restrict__ out) {
  __shared__ bf16 At[128 * 32];
  __shared__ bf16 Bt[128 * 32];
  int b = blockIdx.z, mt = blockIdx.y, ot = blockIdx.x;
  int m0 = mt * 128, o0 = ot * 128;
  int t = threadIdx.x, w = t >> 6, l = t & 63;
  f32x4 acc[4][4] = {};
  gemm_bt_core(ont + ((size_t)b * 1024 + m0) * 512, pwb + (size_t)o0 * 512, At, Bt, acc, w, l);

  int wr = w >> 1, wc = w & 1, quad = l >> 4, li = l & 15;
#pragma unroll
  for (int i = 0; i < 4; i++) {
    int gn = m0 + wr * 64 + i * 16 + quad * 4;
#pragma unroll
    for (int j = 0; j < 4; j++) {
      int go = o0 + wc * 64 + j * 16 + li;
      float bias = pb[go];
      F4 xres; xres.v = *(const float4*)(x + ((size_t)b * 512 + go) * 1024 + gn);
      F4 o;
#pragma unroll
      for (int r = 0; r < 4; r++) o.f[r] = acc[i][j][r] + bias + xres.f[r];
      *(float4*)(out + ((size_t)b * 512 + go) * 1024 + gn) = o.v;
    }
  }
}

// ---------------------------------------------------------------------------
extern "C" void kernel_launch(void* const* d_in, const int* in_sizes, int n_in,
                              void* d_out, int out_size, void* d_ws, size_t ws_size,
                              hipStream_t stream) {
  const float* x  = (const float*)d_in[0];
  const float* nw = (const float*)d_in[1];
  const float* nb = (const float*)d_in[2];
  const float* qw = (const float*)d_in[3];
  const float* qb = (const float*)d_in[4];
  const float* pw = (const float*)d_in[5];
  const float* pb = (const float*)d_in[6];
  float* out = (float*)d_out;

  char* ws = (char*)d_ws;
  float2* stats = (float2*)ws;
  bf16* qwb = (bf16*)(ws + (64u << 10));
  bf16* pwb = (bf16*)(ws + (2u << 20));
  bf16* hnt = (bf16*)(ws + (4u << 20));   // reused as ont after qkv_gemm
  bf16* qkt = (bf16*)(ws + (20u << 20));
  bf16* vt  = (bf16*)(ws + (52u << 20));
  bf16* ont = hnt;

  cvt_w<<<1024, 256, 0, stream>>>(qw, pw, qwb, pwb);
  gn_stats<<<512, 256, 0, stream>>>(x, stats);
  gn_apply<<<dim3(4, 16, 16), 256, 0, stream>>>(x, nw, nb, stats, hnt);
  qkv_gemm<<<dim3(12, 8, 16), 256, 0, stream>>>(hnt, qwb, qb, qkt, vt);
  attn<<<dim3(128, 8, 1), 256, 0, stream>>>(qkt, vt, ont);
  proj_gemm<<<dim3(4, 8, 16), 256, 0, stream>>>(ont, pwb, pb, x, out);
}

// Round 7
// 230.109 us; speedup vs baseline: 1.4754x; 1.4754x over previous
//
#include <hip/hip_runtime.h>
#include <cstdint>
#include <math.h>

// ---------------------------------------------------------------------------
// AttentionBlock: GroupNorm(32) -> 1x1 conv QKV -> MHA(8 heads, hd=64)
//                 -> 1x1 conv proj -> +residual.   B=16, C=512, N=H*W=1024.
// I/O tensors are FP32. Internal math: bf16 MFMA.
//
// Q/K/V are stored FRAGMENT-ORDERED per (b,h) so attention loads are fully
// coalesced single-burst reads:
//   qsw/ksw (A/B-frag of 16x16x32): per (blk=n>>4, ks=d>>5) 512-elem tile,
//       elem = ((blk*2+ks)*512) + ((n&15)*4 + ((d&31)>>3))*8 + (d&7)
//   vsw (A-frag of 16x16x16):       per (kblk=k>>4, df=d>>4) 256-elem tile,
//       elem = ((kblk*4+df)*256) + ((d&15)*4 + ((k&15)>>2))*4 + (k&3)
//
// ws layout (byte offsets):
//   0    stats float2[512] | 64K qwb bf16[1536*512] | 2M pwb bf16[512*512]
//   4M   hnt (B,N,C) bf16  (reused as ont)
//   20M  qsw | 36M ksw | 52M vsw   (16 MB each, 128 KB per (b,h))
// ---------------------------------------------------------------------------

typedef __bf16 bf16;
typedef __attribute__((ext_vector_type(8))) __bf16 bf16x8;
typedef __attribute__((ext_vector_type(4))) float f32x4;
typedef __attribute__((ext_vector_type(4))) short s16x4;

union U8 { uint4 u4; bf16x8 v; bf16 h[8]; };
union U4 { ushort4 u; bf16 h[4]; };
union UB4 { ushort4 u; s16x4 s; bf16 h[4]; };
union F4 { float4 v; float f[4]; };

typedef __attribute__((address_space(1))) void* gp1;
typedef __attribute__((address_space(3))) void* lp3;

__device__ __forceinline__ void async16(const void* g, void* l) {
  __builtin_amdgcn_global_load_lds((gp1)g, (lp3)l, 16, 0, 0);
}

#define LOG2E 1.44269504f

// ---------------------------------------------------------------------------
// Kernel 0: convert fp32 weights to bf16. qw: 1536x512, pw: 512x512.
// ---------------------------------------------------------------------------
__global__ __launch_bounds__(256) void cvt_w(const float* __restrict__ qw,
                                             const float* __restrict__ pw,
                                             bf16* __restrict__ qwb,
                                             bf16* __restrict__ pwb) {
  int i = blockIdx.x * 256 + threadIdx.x;     // float4 index; 262144 total
  F4 v; bf16* dst;
  if (i < 196608) { v.v = ((const float4*)qw)[i]; dst = qwb + (size_t)i * 4; }
  else { v.v = ((const float4*)pw)[i - 196608]; dst = pwb + (size_t)(i - 196608) * 4; }
  U4 o;
#pragma unroll
  for (int j = 0; j < 4; j++) o.h[j] = (bf16)v.f[j];
  *(ushort4*)dst = o.u;
}

// ---------------------------------------------------------------------------
// Kernel 1: per-(b,group) mean/rstd. One block per (b,g): 16ch x 1024 fp32.
// ---------------------------------------------------------------------------
__global__ __launch_bounds__(256) void gn_stats(const float* __restrict__ x,
                                                float2* __restrict__ stats) {
  int bg = blockIdx.x;                         // b*32 + g
  const float* base = x + (size_t)bg * 16384;
  int t = threadIdx.x;
  float s = 0.f, ss = 0.f;
#pragma unroll
  for (int p = 0; p < 16; p++) {
    F4 u; u.v = *(const float4*)(base + (size_t)(p * 256 + t) * 4);
#pragma unroll
    for (int i = 0; i < 4; i++) { float v = u.f[i]; s += v; ss += v * v; }
  }
  for (int off = 1; off < 64; off <<= 1) { s += __shfl_xor(s, off); ss += __shfl_xor(ss, off); }
  __shared__ float red[8];
  int w = t >> 6;
  if ((t & 63) == 0) { red[w] = s; red[4 + w] = ss; }
  __syncthreads();
  if (t == 0) {
    float S = red[0] + red[1] + red[2] + red[3];
    float SS = red[4] + red[5] + red[6] + red[7];
    float mean = S * (1.f / 16384.f);
    float var = SS * (1.f / 16384.f) - mean * mean;
    stats[bg] = make_float2(mean, rsqrtf(var + 1e-5f));
  }
}

// ---------------------------------------------------------------------------
// Kernel 2: hn_t[b][n][c] = bf16((x[b][c][n]-mean)*rstd*w + bias), transposed.
// ---------------------------------------------------------------------------
__global__ __launch_bounds__(256) void gn_apply(const float* __restrict__ x,
                                                const float* __restrict__ nwp,
                                                const float* __restrict__ nbp,
                                                const float2* __restrict__ stats,
                                                bf16* __restrict__ hnt) {
  int b = blockIdx.z, nt = blockIdx.y, ct = blockIdx.x;
  int t = threadIdx.x, w = t >> 6, l = t & 63;
  int wc = w & 1, wn = w >> 1;
  int cb = ct * 128 + wc * 64 + (l & 7) * 8;   // 8 channels per lane
  int n0 = nt * 64 + wn * 32 + (l >> 3) * 4;   // 4 n per lane
  float2 ms = stats[b * 32 + (cb >> 4)];
  float wgt[8], bia[8];
#pragma unroll
  for (int i = 0; i < 8; i++) {
    float wi = nwp[cb + i] * ms.y;
    wgt[i] = wi;
    bia[i] = nbp[cb + i] - ms.x * wi;
  }
  F4 in[8];
  const float* xb = x + ((size_t)b * 512 + cb) * 1024 + n0;
#pragma unroll
  for (int i = 0; i < 8; i++) in[i].v = *(const float4*)(xb + (size_t)i * 1024);
  bf16* ob = hnt + ((size_t)b * 1024 + n0) * 512 + cb;
#pragma unroll
  for (int j = 0; j < 4; j++) {
    U8 o;
#pragma unroll
    for (int i = 0; i < 8; i++) o.h[i] = (bf16)(in[i].f[j] * wgt[i] + bia[i]);
    *(uint4*)(ob + (size_t)j * 512) = o.u4;
  }
}

// ---------------------------------------------------------------------------
// Shared gemm-BT core (m97 recipe).
// ---------------------------------------------------------------------------
__device__ __forceinline__ void gemm_bt_core(const bf16* ga0, const bf16* gb0,
                                             bf16* At, bf16* Bt,
                                             f32x4 (&acc)[4][4], int w, int l) {
  const bf16* ga = ga0 + (size_t)(w * 16 + (l >> 2)) * 512 + (l & 3) * 8;
  const bf16* gb = gb0 + (size_t)(w * 16 + (l >> 2)) * 512 + (l & 3) * 8;
  int wr = w >> 1, wc = w & 1;
  const bf16* Ab = At + (wr * 64 + (l & 15)) * 32 + (l >> 4) * 8;
  const bf16* Bb = Bt + (wc * 64 + (l & 15)) * 32 + (l >> 4) * 8;
  bf16* lA = At + w * 16 * 32;
  bf16* lB = Bt + w * 16 * 32;
  for (int k0 = 0; k0 < 512; k0 += 32) {
    async16(ga + k0, lA);
    async16(ga + 64 * 512 + k0, lA + 64 * 32);
    async16(gb + k0, lB);
    async16(gb + 64 * 512 + k0, lB + 64 * 32);
    __syncthreads();
    bf16x8 af[4], bfr[4];
#pragma unroll
    for (int i = 0; i < 4; i++) {
      af[i] = *(const bf16x8*)(Ab + i * 512);
      bfr[i] = *(const bf16x8*)(Bb + i * 512);
    }
#pragma unroll
    for (int i = 0; i < 4; i++)
#pragma unroll
      for (int j = 0; j < 4; j++)
        acc[i][j] = __builtin_amdgcn_mfma_f32_16x16x32_bf16(af[i], bfr[j], acc[i][j], 0, 0, 0);
    __syncthreads();
  }
}

// ---------------------------------------------------------------------------
// Kernel 3: qkv projection GEMM; epilogue writes FRAGMENT-ORDERED q/k/v.
// Grid (ot=12, nt=8, b=16). ot 0..3 -> qsw, 4..7 -> ksw, 8..11 -> vsw.
// ---------------------------------------------------------------------------
__global__ __launch_bounds__(256, 2) void qkv_gemm(const bf16* __restrict__ hnt,
                                                   const bf16* __restrict__ qwb,
                                                   const float* __restrict__ qb,
                                                   bf16* __restrict__ qsw,
                                                   bf16* __restrict__ ksw,
                                                   bf16* __restrict__ vsw) {
  __shared__ bf16 At[128 * 32];
  __shared__ bf16 Bt[128 * 32];
  int b = blockIdx.z, mt = blockIdx.y, ot = blockIdx.x;
  int m0 = mt * 128, o0 = ot * 128;
  int t = threadIdx.x, w = t >> 6, l = t & 63;
  f32x4 acc[4][4] = {};
  gemm_bt_core(hnt + ((size_t)b * 1024 + m0) * 512, qwb + (size_t)o0 * 512, At, Bt, acc, w, l);

  int wr = w >> 1, wc = w & 1, quad = l >> 4, li = l & 15;
#pragma unroll
  for (int i = 0; i < 4; i++) {
    int gnb = m0 + wr * 64 + i * 16;      // 16-aligned n-block base
    int blk = gnb >> 4;                   // n-block (= k-block for K/V)
#pragma unroll
    for (int j = 0; j < 4; j++) {
      int go = o0 + wc * 64 + j * 16 + li;
      float bias = qb[go];
      if (ot < 8) {                       // q or k: frag-ordered 2B stores
        int c = (ot < 4) ? go : (go - 512);
        int hh = c >> 6, d = c & 63;
        int ks = d >> 5, dq = (d >> 3) & 3, jj = d & 7;
        bf16* base = ((ot < 4) ? qsw : ksw) + ((size_t)(b * 8 + hh) << 16)
                     + (blk * 2 + ks) * 512 + dq * 8 + jj;
#pragma unroll
        for (int r = 0; r < 4; r++)
          base[(quad * 4 + r) * 32] = (bf16)(acc[i][j][r] + bias);
      } else {                            // v: frag-ordered packed 8B stores
        int c = go - 1024;
        int hh = c >> 6, d = c & 63;
        int df = d >> 4, lv = d & 15;
        bf16* base = vsw + ((size_t)(b * 8 + hh) << 16)
                     + (blk * 4 + df) * 256 + (lv * 4 + quad) * 4;
        U4 pk;
#pragma unroll
        for (int r = 0; r < 4; r++) pk.h[r] = (bf16)(acc[i][j][r] + bias);
        *(ushort4*)base = pk.u;
      }
    }
  }
}

// ---------------------------------------------------------------------------
// Kernel 4: flash attention, S^T formulation, zero LDS, chunked softmax,
// fragment-ordered coalesced loads (every load = one contiguous 512B/1KB
// burst; per-chunk addressing = one base + constant offsets).
// Grid (bh=128, qt=8): all 8 q-tiles of one (b,h) share an XCD.
// ---------------------------------------------------------------------------
__global__ __launch_bounds__(256, 4) void attn(const bf16* __restrict__ qsw,
                                               const bf16* __restrict__ ksw,
                                               const bf16* __restrict__ vsw,
                                               bf16* __restrict__ ont) {
  int bh = blockIdx.x;                 // b*8 + h
  int b = bh >> 3, h = bh & 7;
  int qt = blockIdx.y;
  int t = threadIdx.x, w = t >> 6, l = t & 63;
  int quad = l >> 4, li = l & 15;
  int q0 = qt * 128 + w * 32;

  int laneK = (li * 4 + quad) * 8;     // 16B-chunk lane offset (elems)
  int laneV = (li * 4 + quad) * 4;     // 8B-chunk lane offset (elems)
  const bf16* qp = qsw + ((size_t)bh << 16) + laneK;
  const bf16* kp = ksw + ((size_t)bh << 16) + laneK;
  const bf16* vp = vsw + ((size_t)bh << 16) + laneV;

  // Q frags (B-operand of 16x16x32): scale = 0.125 * log2(e) folded in.
  const float QS = 0.125f * LOG2E;
  bf16x8 qfr[2][2];
#pragma unroll
  for (int qf = 0; qf < 2; qf++)
#pragma unroll
    for (int ks = 0; ks < 2; ks++) {
      U8 u;
      u.u4 = *(const uint4*)(qp + (((q0 >> 4) + qf) * 2 + ks) * 512);
#pragma unroll
      for (int i = 0; i < 8; i++) u.h[i] = (bf16)((float)u.h[i] * QS);
      qfr[qf][ks] = u.v;
    }

  float mrun[2] = {-INFINITY, -INFINITY}, lrun[2] = {0.f, 0.f};
  f32x4 of[4][2] = {};   // O^T accum [df][qf]: row d=df*16+quad*4+r, col q=qf*16+li

  // ---- prefetch K chunk 0 (2 k-blocks x 2 d-halves) ----
  U8 ka[2], kc[2];
#pragma unroll
  for (int kf = 0; kf < 2; kf++) {
    ka[kf].u4 = *(const uint4*)(kp + kf * 1024);
    kc[kf].u4 = *(const uint4*)(kp + kf * 1024 + 512);
  }

  for (int c = 0; c < 32; c++) {
    int cb = c * 2048;
    // ---- V frags for THIS chunk: 8 coalesced 8B loads ----
    UB4 va[2][4];
#pragma unroll
    for (int kf = 0; kf < 2; kf++)
#pragma unroll
      for (int df = 0; df < 4; df++)
        va[kf][df].u = *(const ushort4*)(vp + cb + kf * 1024 + df * 256);
    // ---- S^T chunk: st[qf][kf], k = c*32 + kf*16 + quad*4 + r, q = qf*16+li
    f32x4 st[2][2] = {};
#pragma unroll
    for (int kf = 0; kf < 2; kf++) {
      st[0][kf] = __builtin_amdgcn_mfma_f32_16x16x32_bf16(ka[kf].v, qfr[0][0], st[0][kf], 0, 0, 0);
      st[1][kf] = __builtin_amdgcn_mfma_f32_16x16x32_bf16(ka[kf].v, qfr[1][0], st[1][kf], 0, 0, 0);
      st[0][kf] = __builtin_amdgcn_mfma_f32_16x16x32_bf16(kc[kf].v, qfr[0][1], st[0][kf], 0, 0, 0);
      st[1][kf] = __builtin_amdgcn_mfma_f32_16x16x32_bf16(kc[kf].v, qfr[1][1], st[1][kf], 0, 0, 0);
    }
    // ---- prefetch K for NEXT chunk (wrap on last iter; result unused) ----
    int cn = ((c + 1) & 31) * 2048;
    U8 nka[2], nkc[2];
#pragma unroll
    for (int kf = 0; kf < 2; kf++) {
      nka[kf].u4 = *(const uint4*)(kp + cn + kf * 1024);
      nkc[kf].u4 = *(const uint4*)(kp + cn + kf * 1024 + 512);
    }
    // ---- online softmax over the 32-k chunk ----
    UB4 pfr[2][2];
#pragma unroll
    for (int qf = 0; qf < 2; qf++) {
      f32x4 vm = st[qf][0];
#pragma unroll
      for (int r = 0; r < 4; r++) vm[r] = fmaxf(vm[r], st[qf][1][r]);
      float mt = fmaxf(fmaxf(vm[0], vm[1]), fmaxf(vm[2], vm[3]));
      mt = fmaxf(mt, __shfl_xor(mt, 16));
      mt = fmaxf(mt, __shfl_xor(mt, 32));
      float mold = mrun[qf];
      float mnew = fmaxf(mold, mt);
      mrun[qf] = mnew;
      f32x4 vs = {};
#pragma unroll
      for (int kf = 0; kf < 2; kf++)
#pragma unroll
        for (int r = 0; r < 4; r++) {
          float e = __builtin_amdgcn_exp2f(st[qf][kf][r] - mnew);
          vs[r] += e;
          pfr[qf][kf].h[r] = (bf16)e;
        }
      float ls = (vs[0] + vs[1]) + (vs[2] + vs[3]);
      ls += __shfl_xor(ls, 16);
      ls += __shfl_xor(ls, 32);
      if (__ballot(mnew > mold)) {       // any lane saw a new max -> rescale
        float alpha = __builtin_amdgcn_exp2f(mold - mnew);
        lrun[qf] = lrun[qf] * alpha + ls;
#pragma unroll
        for (int df = 0; df < 4; df++)
#pragma unroll
          for (int r = 0; r < 4; r++) of[df][qf][r] *= alpha;
      } else {
        lrun[qf] += ls;
      }
    }
    // ---- O^T += V^T P^T (16x16x16, P^T straight from registers) ----
#pragma unroll
    for (int kf = 0; kf < 2; kf++)
#pragma unroll
      for (int df = 0; df < 4; df++)
#pragma unroll
        for (int qf = 0; qf < 2; qf++)
          of[df][qf] = __builtin_amdgcn_mfma_f32_16x16x16bf16_1k(va[kf][df].s, pfr[qf][kf].s, of[df][qf], 0, 0, 0);
    // ---- rotate K double-buffer ----
#pragma unroll
    for (int kf = 0; kf < 2; kf++) { ka[kf] = nka[kf]; kc[kf] = nkc[kf]; }
  }
  // ---- epilogue: O[q][d] = O^T/l, packed 8B stores into (n,c) layout ----
#pragma unroll
  for (int qf = 0; qf < 2; qf++) {
    float inv = 1.f / lrun[qf];
    bf16* ob = ont + ((size_t)b * 1024 + q0 + qf * 16 + li) * 512 + h * 64 + quad * 4;
#pragma unroll
    for (int df = 0; df < 4; df++) {
      U4 pk;
#pragma unroll
      for (int r = 0; r < 4; r++) pk.h[r] = (bf16)(of[df][qf][r] * inv);
      *(ushort4*)(ob + df * 16) = pk.u;
    }
  }
}

// ---------------------------------------------------------------------------
// Kernel 5: proj GEMM + residual. Grid (4, 8, 16).
// ---------------------------------------------------------------------------
__global__ __launch_bounds__(256, 2) void proj_gemm(const bf16* __restrict__ ont,
                                                    const bf16* __restrict__ pwb,
                                                    const float* __restrict__ pb,
                                                    const float* __restrict__ x,
                                                    float* __restrict__ out) {
  __shared__ bf16 At[128 * 32];
  __shared__ bf16 Bt[128 * 32];
  int b = blockIdx.z, mt = blockIdx.y, ot = blockIdx.x;
  int m0 = mt * 128, o0 = ot * 128;
  int t = threadIdx.x, w = t >> 6, l = t & 63;
  f32x4 acc[4][4] = {};
  gemm_bt_core(ont + ((size_t)b * 1024 + m0) * 512, pwb + (size_t)o0 * 512, At, Bt, acc, w, l);

  int wr = w >> 1, wc = w & 1, quad = l >> 4, li = l & 15;
#pragma unroll
  for (int i = 0; i < 4; i++) {
    int gn = m0 + wr * 64 + i * 16 + quad * 4;
#pragma unroll
    for (int j = 0; j < 4; j++) {
      int go = o0 + wc * 64 + j * 16 + li;
      float bias = pb[go];
      F4 xres; xres.v = *(const float4*)(x + ((size_t)b * 512 + go) * 1024 + gn);
      F4 o;
#pragma unroll
      for (int r = 0; r < 4; r++) o.f[r] = acc[i][j][r] + bias + xres.f[r];
      *(float4*)(out + ((size_t)b * 512 + go) * 1024 + gn) = o.v;
    }
  }
}

// ---------------------------------------------------------------------------
extern "C" void kernel_launch(void* const* d_in, const int* in_sizes, int n_in,
                              void* d_out, int out_size, void* d_ws, size_t ws_size,
                              hipStream_t stream) {
  const float* x  = (const float*)d_in[0];
  const float* nw = (const float*)d_in[1];
  const float* nb = (const float*)d_in[2];
  const float* qw = (const float*)d_in[3];
  const float* qb = (const float*)d_in[4];
  const float* pw = (const float*)d_in[5];
  const float* pb = (const float*)d_in[6];
  float* out = (float*)d_out;

  char* ws = (char*)d_ws;
  float2* stats = (float2*)ws;
  bf16* qwb = (bf16*)(ws + (64u << 10));
  bf16* pwb = (bf16*)(ws + (2u << 20));
  bf16* hnt = (bf16*)(ws + (4u << 20));   // reused as ont after qkv_gemm
  bf16* qsw = (bf16*)(ws + (20u << 20));
  bf16* ksw = (bf16*)(ws + (36u << 20));
  bf16* vsw = (bf16*)(ws + (52u << 20));
  bf16* ont = hnt;

  cvt_w<<<1024, 256, 0, stream>>>(qw, pw, qwb, pwb);
  gn_stats<<<512, 256, 0, stream>>>(x, stats);
  gn_apply<<<dim3(4, 16, 16), 256, 0, stream>>>(x, nw, nb, stats, hnt);
  qkv_gemm<<<dim3(12, 8, 16), 256, 0, stream>>>(hnt, qwb, qb, qsw, ksw, vsw);
  attn<<<dim3(128, 8, 1), 256, 0, stream>>>(qsw, ksw, vsw, ont);
  proj_gemm<<<dim3(4, 8, 16), 256, 0, stream>>>(ont, pwb, pb, x, out);
}